// Round 16
// baseline (222.759 us; speedup 1.0000x reference)
//
#include <hip/hip_runtime.h>
#include <cstdint>
#include <cstddef>

// Problem: x += ssm_scan(rmsnorm(x,s1)); out = x + gelu(rmsnorm(x,s2)@w1+b1)@w2+b2
// B=4 L=2048 D=1024 N=16 DFF=4096, f32 in/out. bf16 MFMA GEMMs (r12 pair) + fused smalls.

#define BATCH 4
#define SEQLEN 2048
#define DMODEL 1024
#define NSTATE 16
#define DFF 4096
#define NCH 128    // chunks over L
#define LCH 16     // SEQLEN / NCH

typedef unsigned short ushort_t;
typedef __attribute__((ext_vector_type(8))) short short8;
typedef __attribute__((ext_vector_type(4))) float f32x4;

__device__ __forceinline__ ushort_t f2bf(float f) {
  uint32_t u = __builtin_bit_cast(uint32_t, f);
  uint32_t r = (u + 0x7FFFu + ((u >> 16) & 1u)) >> 16;
  return (ushort_t)r;
}

// ---------------- coefficient precompute ----------------
__global__ void coef_kernel(const float* __restrict__ A_ssm, const float* __restrict__ B_ssm,
                            const float* __restrict__ C_ssm,
                            float* __restrict__ dA_t, float* __restrict__ dBz_t,
                            float* __restrict__ dAc_t, float* __restrict__ Ct) {
  int d = blockIdx.x * 256 + threadIdx.x;
  if (d >= DMODEL) return;
  const float l0 = -6.907755278982137f;       // log(0.001)
  const float ld = 0.30701134573253947f;      // log(100)/15
  for (int n = 0; n < NSTATE; n++) {
    float dt = expf(l0 + (float)n * ld);
    float a  = A_ssm[d * NSTATE + n];
    float ea = expf(a);
    float da = expf(-ea * dt);
    float dbz = B_ssm[d * NSTATE + n] * (1.f - da) / ea;
    float dac = expf(-ea * dt * (float)LCH);
    dA_t [n * DMODEL + d] = da;
    dBz_t[n * DMODEL + d] = dbz;
    dAc_t[n * DMODEL + d] = dac;
    Ct   [n * DMODEL + d] = C_ssm[d * NSTATE + n];
  }
}

// ---------------- transpose f32 [R][C] -> bf16 [C][R] ----------------
__global__ void transpose_to_bf16(const float* __restrict__ src, ushort_t* __restrict__ dst,
                                  int R, int C) {
  __shared__ float tile[32][33];
  int bx = blockIdx.x * 32, by = blockIdx.y * 32;
  int tx = threadIdx.x, ty = threadIdx.y;
  #pragma unroll
  for (int i = 0; i < 4; i++) {
    int r = by + ty + i * 8;
    tile[ty + i * 8][tx] = src[(size_t)r * C + bx + tx];
  }
  __syncthreads();
  #pragma unroll
  for (int i = 0; i < 4; i++) {
    int c = bx + ty + i * 8;
    dst[(size_t)c * R + by + tx] = f2bf(tile[tx][ty + i * 8]);
  }
}

// ======== fused1: rmsnorm1 (per-row rrms) + scan pass1 (chunk-local finals) ========
// grid 512 = (b<<7)|c, 1024 threads. Phase1: wave w computes rrms of row w (16 rows/block)
// into LDS. Phase2: thread d scans its column over the chunk's 16 steps (x L2-hot).
__global__ void fused_scan1(const float* __restrict__ x, const float* __restrict__ scale1,
                            const float* __restrict__ dA_t, const float* __restrict__ dBz_t,
                            float* __restrict__ s_fin) {
  const int b = blockIdx.x >> 7, c = blockIdx.x & 127;
  const int tid = threadIdx.x, wave = tid >> 6, lane = tid & 63;
  __shared__ float rrmsL[LCH];

  {   // phase 1: rrms for row `wave`
    const float4* p = (const float4*)(x + ((size_t)b * SEQLEN + (size_t)c * LCH + wave) * DMODEL);
    float s = 0.f;
    #pragma unroll
    for (int w = 0; w < 4; w++) {
      float4 v = p[w * 64 + lane];
      s += v.x * v.x + v.y * v.y + v.z * v.z + v.w * v.w;
    }
    #pragma unroll
    for (int off = 32; off; off >>= 1) s += __shfl_xor(s, off, 64);
    if (lane == 0) rrmsL[wave] = rsqrtf(s * (1.f / DMODEL) + 1e-6f);
  }
  __syncthreads();

  // phase 2: scan column d = tid
  const int d = tid;
  float dA[NSTATE], dBz[NSTATE], s[NSTATE];
  #pragma unroll
  for (int n = 0; n < NSTATE; n++) {
    dA[n] = dA_t[n * DMODEL + d];
    dBz[n] = dBz_t[n * DMODEL + d];
    s[n] = 0.f;
  }
  const float sc1 = scale1[d];
  const float* xp = x + ((size_t)b * SEQLEN + (size_t)c * LCH) * DMODEL + d;
  #pragma unroll
  for (int t = 0; t < LCH; t++) {
    float u = xp[(size_t)t * DMODEL] * rrmsL[t] * sc1;
    #pragma unroll
    for (int n = 0; n < NSTATE; n++) s[n] = fmaf(s[n], dA[n], u * dBz[n]);
  }
  #pragma unroll
  for (int n = 0; n < NSTATE; n++)
    s_fin[(((size_t)n * BATCH + b) * NCH + c) * DMODEL + d] = s[n];
}

// ---------------- scan pass2: serial chunk-carry combine (128 chunks) ----------------
__global__ void scan_pass2(const float* __restrict__ s_fin, const float* __restrict__ dAc_t,
                           float* __restrict__ s_in) {
  int idx = blockIdx.x * 256 + threadIdx.x;  // BATCH*DMODEL*NSTATE = 65536
  int d = idx & (DMODEL - 1);
  int b = (idx >> 10) & (BATCH - 1);
  int n = idx >> 12;
  float dc = dAc_t[n * DMODEL + d];
  float s = 0.f;
  for (int c = 0; c < NCH; c++) {
    size_t o = (((size_t)n * BATCH + b) * NCH + c) * DMODEL + d;
    s_in[o] = s;
    s = s_fin[o] + dc * s;
  }
}

// ======== fused3: scan pass3 (x2 = x + y + u*D) + rmsnorm2 (hb = bf16 normed) ========
// grid 512 = (b<<7)|c, 1024 threads. Phase0: rrms(x rows) -> LDS. Phase1: thread-d scan
// with carry-in, writes x2. __syncthreads (vmcnt-drain) publishes x2. Phase2: wave w
// rms-norms x2 row w (L2-hot) and writes hb.
__global__ void fused_scan3(const float* __restrict__ x, const float* __restrict__ scale1,
                            const float* __restrict__ scale2,
                            const float* __restrict__ dA_t, const float* __restrict__ dBz_t,
                            const float* __restrict__ Ct, const float* __restrict__ Dv,
                            const float* __restrict__ s_in,
                            float* __restrict__ out, ushort_t* __restrict__ hb) {
  const int b = blockIdx.x >> 7, c = blockIdx.x & 127;
  const int tid = threadIdx.x, wave = tid >> 6, lane = tid & 63;
  const size_t rowBase = (size_t)b * SEQLEN + (size_t)c * LCH;
  __shared__ float rrmsL[LCH];

  {   // phase 0: rrms(x) for row `wave`
    const float4* p = (const float4*)(x + (rowBase + wave) * DMODEL);
    float s = 0.f;
    #pragma unroll
    for (int w = 0; w < 4; w++) {
      float4 v = p[w * 64 + lane];
      s += v.x * v.x + v.y * v.y + v.z * v.z + v.w * v.w;
    }
    #pragma unroll
    for (int off = 32; off; off >>= 1) s += __shfl_xor(s, off, 64);
    if (lane == 0) rrmsL[wave] = rsqrtf(s * (1.f / DMODEL) + 1e-6f);
  }
  __syncthreads();

  {   // phase 1: scan column d = tid, write x2
    const int d = tid;
    float dA[NSTATE], dBz[NSTATE], Cc[NSTATE], s[NSTATE];
    #pragma unroll
    for (int n = 0; n < NSTATE; n++) {
      dA[n] = dA_t[n * DMODEL + d];
      dBz[n] = dBz_t[n * DMODEL + d];
      Cc[n] = Ct[n * DMODEL + d];
      s[n] = s_in[(((size_t)n * BATCH + b) * NCH + c) * DMODEL + d];
    }
    const float sc1 = scale1[d], Dd = Dv[d];
    const float* xp = x + rowBase * DMODEL + d;
    float* op = out + rowBase * DMODEL + d;
    #pragma unroll
    for (int t = 0; t < LCH; t++) {
      float xv = xp[(size_t)t * DMODEL];
      float u = xv * rrmsL[t] * sc1;
      float y = 0.f;
      #pragma unroll
      for (int n = 0; n < NSTATE; n++) {
        s[n] = fmaf(s[n], dA[n], u * dBz[n]);
        y = fmaf(Cc[n], s[n], y);
      }
      op[(size_t)t * DMODEL] = xv + y + u * Dd;
    }
  }
  __syncthreads();   // compiler drains vmcnt before s_barrier -> x2 visible block-wide

  {   // phase 2: rmsnorm2 of x2 row `wave` -> hb (bf16)
    const float4* p = (const float4*)(out + (rowBase + wave) * DMODEL);
    float4 v[4];
    float s = 0.f;
    #pragma unroll
    for (int w = 0; w < 4; w++) {
      v[w] = p[w * 64 + lane];
      s += v[w].x * v[w].x + v[w].y * v[w].y + v[w].z * v[w].z + v[w].w * v[w].w;
    }
    #pragma unroll
    for (int off = 32; off; off >>= 1) s += __shfl_xor(s, off, 64);
    float r = rsqrtf(s * (1.f / DMODEL) + 1e-6f);
    const float4* sc = (const float4*)scale2;
    ushort_t* hrow = hb + (rowBase + wave) * DMODEL;
    #pragma unroll
    for (int w = 0; w < 4; w++) {
      float4 scv = sc[w * 64 + lane];
      ushort4 u;
      u.x = f2bf(v[w].x * r * scv.x);
      u.y = f2bf(v[w].y * r * scv.y);
      u.z = f2bf(v[w].z * r * scv.z);
      u.w = f2bf(v[w].w * r * scv.w);
      *(ushort4*)(hrow + (size_t)(w * 64 + lane) * 4) = u;
    }
  }
}

template <int N>
__device__ __forceinline__ void fence_vm() {
  asm volatile("s_waitcnt vmcnt(%0)" :: "n"(N) : "memory");
}

__device__ __forceinline__ void bar() { asm volatile("s_barrier" ::: "memory"); }

__device__ __forceinline__ void gl2lds16(const ushort_t* g, ushort_t* l) {
  __builtin_amdgcn_global_load_lds(
      (const __attribute__((address_space(1))) unsigned int*)g,
      (__attribute__((address_space(3))) unsigned int*)l, 16, 0, 0);
}

// ========== gemm1 (r12-verbatim): 256x256, BK=64, 2-slot, 16 waves, wave 64x64 ==========
template <int K>
__global__ __launch_bounds__(1024, 4) void gemm_w64(const ushort_t* __restrict__ A,
                                                    const ushort_t* __restrict__ B,
                                                    const float* __restrict__ bias,
                                                    ushort_t* __restrict__ outp,
                                                    int M, int N) {
  constexpr int SLOT = 32768;               // elems: A 256x64 + B 256x64 (64 KB)
  constexpr int NT = K / 64;
  __shared__ __align__(16) ushort_t lds[2 * SLOT];   // 128 KB

  const int tid = threadIdx.x;
  const int wave = tid >> 6, lane = tid & 63;
  const int wr = wave >> 2, wc = wave & 3;

  const int nwg = gridDim.x, cpx = nwg >> 3, bid = blockIdx.x;
  const int wg = (bid & 7) * cpx + (bid >> 3);
  const int nbn = N / 256;
  const int m0 = (wg / nbn) * 256, n0 = (wg % nbn) * 256;

  const int scol = 8 * ((tid & 7) ^ ((tid >> 3) & 7));
  const int wo = wave * 512;
  const ushort_t* aStg = A + (size_t)(m0 + (tid >> 3)) * K + scol;
  const ushort_t* aStg2 = aStg + (size_t)128 * K;
  const ushort_t* bStg = B + (size_t)(n0 + (tid >> 3)) * K + scol;
  const ushort_t* bStg2 = bStg + (size_t)128 * K;

  f32x4 acc[4][4] = {};

  {
    ushort_t* d = lds + wo;
    gl2lds16(aStg,  d);
    gl2lds16(aStg2, d + 8192);
    gl2lds16(bStg,  d + 16384);
    gl2lds16(bStg2, d + 24576);
    aStg += 64; aStg2 += 64; bStg += 64; bStg2 += 64;
  }
  fence_vm<0>(); bar();

  const int rl = lane & 15, c4 = lane >> 4;
  const int sw0 = (c4 ^ (rl & 7)) * 8;
  const int sw1 = ((4 | c4) ^ (rl & 7)) * 8;
  const int aOff = (wr * 64 + rl) * 64;
  const int bOff = 16384 + (wc * 64 + rl) * 64;

  const ushort_t* rSlot = lds;
  ushort_t*       wSlot = lds + SLOT;

  for (int t = 0; t < NT; ++t) {
    if (t + 1 < NT) {
      gl2lds16(aStg,  wSlot + wo);
      gl2lds16(aStg2, wSlot + 8192 + wo);
      gl2lds16(bStg,  wSlot + 16384 + wo);
      gl2lds16(bStg2, wSlot + 24576 + wo);
      aStg += 64; aStg2 += 64; bStg += 64; bStg2 += 64;
    }

    const ushort_t* ra0 = rSlot + aOff + sw0;
    const ushort_t* ra1 = rSlot + aOff + sw1;
    const ushort_t* rb0 = rSlot + bOff + sw0;
    const ushort_t* rb1 = rSlot + bOff + sw1;

    {
      short8 af[4], bf[4];
      #pragma unroll
      for (int m = 0; m < 4; m++) af[m] = *(const short8*)(ra0 + m * 1024);
      #pragma unroll
      for (int n = 0; n < 4; n++) bf[n] = *(const short8*)(rb0 + n * 1024);
      __builtin_amdgcn_s_setprio(1);
      #pragma unroll
      for (int m = 0; m < 4; m++)
        #pragma unroll
        for (int n = 0; n < 4; n++)
          acc[m][n] = __builtin_amdgcn_mfma_f32_16x16x32_bf16(af[m], bf[n], acc[m][n], 0, 0, 0);
      __builtin_amdgcn_s_setprio(0);
    }
    {
      short8 af[4], bf[4];
      #pragma unroll
      for (int m = 0; m < 4; m++) af[m] = *(const short8*)(ra1 + m * 1024);
      #pragma unroll
      for (int n = 0; n < 4; n++) bf[n] = *(const short8*)(rb1 + n * 1024);
      __builtin_amdgcn_s_setprio(1);
      #pragma unroll
      for (int m = 0; m < 4; m++)
        #pragma unroll
        for (int n = 0; n < 4; n++)
          acc[m][n] = __builtin_amdgcn_mfma_f32_16x16x32_bf16(af[m], bf[n], acc[m][n], 0, 0, 0);
      __builtin_amdgcn_s_setprio(0);
    }

    if (t + 1 < NT) { fence_vm<0>(); bar(); }
    const ushort_t* tmp = rSlot; rSlot = wSlot; wSlot = (ushort_t*)tmp;
  }

  const int colb = n0 + wc * 64 + rl;
  const int rowb = m0 + wr * 64 + c4 * 4;
  #pragma unroll
  for (int n = 0; n < 4; n++) {
    int col = colb + n * 16;
    float bs = bias[col];
    #pragma unroll
    for (int m = 0; m < 4; m++) {
      int row = rowb + m * 16;
      #pragma unroll
      for (int j = 0; j < 4; j++) {
        float v = acc[m][n][j] + bs;
        float g = v / (1.f + __expf(-1.702f * v));
        outp[(size_t)(row + j) * N + col] = f2bf(g);
      }
    }
  }
}

// ========== gemm2 (r12-verbatim): 256x128, BK=64, 3-slot, 16 waves, wave 64x32 ==========
template <int K, int MODE>
__global__ __launch_bounds__(1024, 4) void gemm16v(const ushort_t* __restrict__ A,
                                                   const ushort_t* __restrict__ B,
                                                   const float* __restrict__ bias,
                                                   const float* __restrict__ resid,
                                                   void* __restrict__ outp,
                                                   int M, int N) {
  constexpr int TILEA = 16384;
  constexpr int SLOT  = TILEA + 8192;
  constexpr int NT = K / 64;
  __shared__ __align__(16) ushort_t lds[3 * SLOT];   // 144 KB

  const int tid = threadIdx.x;
  const int wave = tid >> 6, lane = tid & 63;
  const int wr = wave >> 2, wc = wave & 3;

  const int nwg = gridDim.x, cpx = nwg >> 3, bid = blockIdx.x;
  const int wg = (bid & 7) * cpx + (bid >> 3);
  const int nbn = N / 128;
  const int m0 = (wg / nbn) * 256, n0 = (wg % nbn) * 128;

  const int scol = 8 * ((tid & 7) ^ ((tid >> 3) & 7));
  const int wo = wave * 512;

  const ushort_t* aStgLo = A + (size_t)(m0 + (tid >> 3)) * K + scol;
  const ushort_t* aStgHi = aStgLo + (size_t)128 * K;
  const ushort_t* bStg   = B + (size_t)(n0 + (tid >> 3)) * K + scol;

  f32x4 acc[4][2] = {};

  {
    ushort_t* s0p = lds;
    gl2lds16(aStgLo, s0p + wo);
    gl2lds16(aStgHi, s0p + 8192 + wo);
    gl2lds16(bStg,   s0p + TILEA + wo);
    ushort_t* s1p = lds + SLOT;
    gl2lds16(aStgLo + 64, s1p + wo);
    gl2lds16(aStgHi + 64, s1p + 8192 + wo);
    gl2lds16(bStg   + 64, s1p + TILEA + wo);
    aStgLo += 128; aStgHi += 128; bStg += 128;
  }
  fence_vm<3>(); bar();

  const int rl = lane & 15, c4 = lane >> 4;
  const int sw0 = (c4 ^ (rl & 7)) * 8;
  const int sw1 = ((4 | c4) ^ (rl & 7)) * 8;
  const int aOff = (wr * 64 + rl) * 64;
  const int bOff = TILEA + (wc * 32 + rl) * 64;

  const ushort_t* rSlot = lds;
  ushort_t*       wSlot = lds + 2 * SLOT;

  for (int t = 0; t < NT; ++t) {
    const ushort_t* ra0 = rSlot + aOff + sw0;
    const ushort_t* ra1 = rSlot + aOff + sw1;
    const ushort_t* rb0 = rSlot + bOff + sw0;
    const ushort_t* rb1 = rSlot + bOff + sw1;

    short8 af[2][4], bf[2][2];
    #pragma unroll
    for (int m = 0; m < 4; m++) {
      af[0][m] = *(const short8*)(ra0 + m * 1024);
      af[1][m] = *(const short8*)(ra1 + m * 1024);
    }
    #pragma unroll
    for (int n = 0; n < 2; n++) {
      bf[0][n] = *(const short8*)(rb0 + n * 1024);
      bf[1][n] = *(const short8*)(rb1 + n * 1024);
    }

    if (t + 2 < NT) {
      gl2lds16(aStgLo, wSlot + wo);
      gl2lds16(aStgHi, wSlot + 8192 + wo);
      gl2lds16(bStg,   wSlot + TILEA + wo);
      aStgLo += 64; aStgHi += 64; bStg += 64;
    }

    __builtin_amdgcn_s_setprio(1);
    #pragma unroll
    for (int kk = 0; kk < 2; kk++)
      #pragma unroll
      for (int m = 0; m < 4; m++)
        #pragma unroll
        for (int n = 0; n < 2; n++)
          acc[m][n] = __builtin_amdgcn_mfma_f32_16x16x32_bf16(af[kk][m], bf[kk][n],
                                                              acc[m][n], 0, 0, 0);
    __builtin_amdgcn_s_setprio(0);

    if (t + 2 < NT) fence_vm<3>();
    else            fence_vm<0>();
    bar();

    const ushort_t* rn = rSlot + SLOT;
    rSlot = (rn == lds + 3 * SLOT) ? lds : rn;
    ushort_t* wn = wSlot + SLOT;
    wSlot = (wn == lds + 3 * SLOT) ? lds : wn;
  }

  const int colb = n0 + wc * 32 + rl;
  const int rowb = m0 + wr * 64 + c4 * 4;
  #pragma unroll
  for (int n = 0; n < 2; n++) {
    int col = colb + n * 16;
    float bs = bias[col];
    #pragma unroll
    for (int m = 0; m < 4; m++) {
      int row = rowb + m * 16;
      #pragma unroll
      for (int j = 0; j < 4; j++) {
        float v = acc[m][n][j] + bs;
        size_t o = (size_t)(row + j) * N + col;
        if (MODE == 1) {
          float g = v / (1.f + __expf(-1.702f * v));
          ((ushort_t*)outp)[o] = f2bf(g);
        } else {
          ((float*)outp)[o] = resid[o] + v;
        }
      }
    }
  }
}

// ---------------- launch ----------------
extern "C" void kernel_launch(void* const* d_in, const int* in_sizes, int n_in,
                              void* d_out, int out_size, void* d_ws, size_t ws_size,
                              hipStream_t stream) {
  (void)in_sizes; (void)n_in; (void)out_size; (void)ws_size;
  const float* x      = (const float*)d_in[0];
  const float* A_ssm  = (const float*)d_in[1];
  const float* B_ssm  = (const float*)d_in[2];
  const float* C_ssm  = (const float*)d_in[3];
  const float* D_ssm  = (const float*)d_in[4];
  const float* scale1 = (const float*)d_in[5];
  const float* scale2 = (const float*)d_in[6];
  const float* w1     = (const float*)d_in[7];
  const float* b1     = (const float*)d_in[8];
  const float* w2     = (const float*)d_in[9];
  const float* b2     = (const float*)d_in[10];
  float* out = (float*)d_out;

  char* ws = (char*)d_ws;
  float*    dA_t  = (float*)(ws + 32768);                     // 64 KB
  float*    dBz_t = (float*)(ws + 98304);                     // 64 KB
  float*    dAc_t = (float*)(ws + 163840);                    // 64 KB
  float*    Ct    = (float*)(ws + 229376);                    // 64 KB
  ushort_t* hb    = (ushort_t*)(ws + 17072128);               // 16 MB
  ushort_t* w1t   = (ushort_t*)(ws + 33849344);               // 8 MB
  ushort_t* w2t   = (ushort_t*)(ws + 42237952);               // 8 MB
  ushort_t* gb    = (ushort_t*)(ws + 50626560);               // 64 MB
  // s_fin/s_in alias the gb region (dead before gemm1 writes gb)
  float*    s_fin = (float*)(ws + 50626560);                  // 32 MB
  float*    s_in  = (float*)(ws + 50626560 + 33554432);       // 32 MB

  const int ROWS = BATCH * SEQLEN;  // 8192

  coef_kernel<<<DMODEL / 256, 256, 0, stream>>>(A_ssm, B_ssm, C_ssm, dA_t, dBz_t, dAc_t, Ct);
  transpose_to_bf16<<<dim3(DFF / 32, DMODEL / 32), dim3(32, 8), 0, stream>>>(w1, w1t, DMODEL, DFF);
  transpose_to_bf16<<<dim3(DMODEL / 32, DFF / 32), dim3(32, 8), 0, stream>>>(w2, w2t, DFF, DMODEL);
  fused_scan1<<<BATCH * NCH, 1024, 0, stream>>>(x, scale1, dA_t, dBz_t, s_fin);
  scan_pass2<<<(BATCH * DMODEL * NSTATE) / 256, 256, 0, stream>>>(s_fin, dAc_t, s_in);
  fused_scan3<<<BATCH * NCH, 1024, 0, stream>>>(x, scale1, scale2, dA_t, dBz_t, Ct,
                                                D_ssm, s_in, out, hb);

  // gemm1: [8192x1024]@[1024x4096] -> gelu -> gb (bf16). 512 blocks, 256x256, BK=64.
  gemm_w64<DMODEL><<<(ROWS / 256) * (DFF / 256), 1024, 0, stream>>>(
      hb, w1t, b1, gb, ROWS, DFF);
  // gemm2: [8192x4096]@[4096x1024] + resid -> out (f32). 256 blocks, 256x128, BK=64.
  gemm16v<DFF, 2><<<(ROWS / 256) * (DMODEL / 128), 1024, 0, stream>>>(
      gb, w2t, b2, out, out, ROWS, DMODEL);
}

// Round 17
// 214.606 us; speedup vs baseline: 1.0380x; 1.0380x over previous
//
#include <hip/hip_runtime.h>
#include <cstdint>
#include <cstddef>

// Problem: x += ssm_scan(rmsnorm(x,s1)); out = x + gelu(rmsnorm(x,s2)@w1+b1)@w2+b2
// B=4 L=2048 D=1024 N=16 DFF=4096, f32 in/out. bf16 MFMA GEMMs (r12 pair) + fused smalls.

#define BATCH 4
#define SEQLEN 2048
#define DMODEL 1024
#define NSTATE 16
#define DFF 4096
#define NCH 64     // chunks over L (64 -> grid 256 = 1 block/CU; state arrays 16 MB)
#define LCH 32     // SEQLEN / NCH

typedef unsigned short ushort_t;
typedef __attribute__((ext_vector_type(8))) short short8;
typedef __attribute__((ext_vector_type(4))) float f32x4;

__device__ __forceinline__ ushort_t f2bf(float f) {
  uint32_t u = __builtin_bit_cast(uint32_t, f);
  uint32_t r = (u + 0x7FFFu + ((u >> 16) & 1u)) >> 16;
  return (ushort_t)r;
}

// ---------------- coefficient precompute ----------------
__global__ void coef_kernel(const float* __restrict__ A_ssm, const float* __restrict__ B_ssm,
                            const float* __restrict__ C_ssm,
                            float* __restrict__ dA_t, float* __restrict__ dBz_t,
                            float* __restrict__ dAc_t, float* __restrict__ Ct) {
  int d = blockIdx.x * 256 + threadIdx.x;
  if (d >= DMODEL) return;
  const float l0 = -6.907755278982137f;       // log(0.001)
  const float ld = 0.30701134573253947f;      // log(100)/15
  for (int n = 0; n < NSTATE; n++) {
    float dt = expf(l0 + (float)n * ld);
    float a  = A_ssm[d * NSTATE + n];
    float ea = expf(a);
    float da = expf(-ea * dt);
    float dbz = B_ssm[d * NSTATE + n] * (1.f - da) / ea;
    float dac = expf(-ea * dt * (float)LCH);
    dA_t [n * DMODEL + d] = da;
    dBz_t[n * DMODEL + d] = dbz;
    dAc_t[n * DMODEL + d] = dac;
    Ct   [n * DMODEL + d] = C_ssm[d * NSTATE + n];
  }
}

// ---------------- transpose f32 [R][C] -> bf16 [C][R] ----------------
__global__ void transpose_to_bf16(const float* __restrict__ src, ushort_t* __restrict__ dst,
                                  int R, int C) {
  __shared__ float tile[32][33];
  int bx = blockIdx.x * 32, by = blockIdx.y * 32;
  int tx = threadIdx.x, ty = threadIdx.y;
  #pragma unroll
  for (int i = 0; i < 4; i++) {
    int r = by + ty + i * 8;
    tile[ty + i * 8][tx] = src[(size_t)r * C + bx + tx];
  }
  __syncthreads();
  #pragma unroll
  for (int i = 0; i < 4; i++) {
    int c = bx + ty + i * 8;
    dst[(size_t)c * R + by + tx] = f2bf(tile[tx][ty + i * 8]);
  }
}

// ======== fused1: rmsnorm1 (per-row rrms) + scan pass1 (chunk-local finals) ========
// grid 256 = (b<<6)|c, 1024 threads. Phase1: wave w computes rrms of rows w, w+16.
// Phase2: thread d scans its column over the chunk's 32 steps (x L2-hot).
__global__ void fused_scan1(const float* __restrict__ x, const float* __restrict__ scale1,
                            const float* __restrict__ dA_t, const float* __restrict__ dBz_t,
                            float* __restrict__ s_fin) {
  const int b = blockIdx.x >> 6, c = blockIdx.x & 63;
  const int tid = threadIdx.x, wave = tid >> 6, lane = tid & 63;
  const size_t rowBase = (size_t)b * SEQLEN + (size_t)c * LCH;
  __shared__ float rrmsL[LCH];

  #pragma unroll
  for (int i = 0; i < 2; i++) {   // phase 1: rrms for rows wave, wave+16
    const int row = wave + 16 * i;
    const float4* p = (const float4*)(x + (rowBase + row) * DMODEL);
    float s = 0.f;
    #pragma unroll
    for (int w = 0; w < 4; w++) {
      float4 v = p[w * 64 + lane];
      s += v.x * v.x + v.y * v.y + v.z * v.z + v.w * v.w;
    }
    #pragma unroll
    for (int off = 32; off; off >>= 1) s += __shfl_xor(s, off, 64);
    if (lane == 0) rrmsL[row] = rsqrtf(s * (1.f / DMODEL) + 1e-6f);
  }
  __syncthreads();

  // phase 2: scan column d = tid
  const int d = tid;
  float dA[NSTATE], dBz[NSTATE], s[NSTATE];
  #pragma unroll
  for (int n = 0; n < NSTATE; n++) {
    dA[n] = dA_t[n * DMODEL + d];
    dBz[n] = dBz_t[n * DMODEL + d];
    s[n] = 0.f;
  }
  const float sc1 = scale1[d];
  const float* xp = x + rowBase * DMODEL + d;
  #pragma unroll 4
  for (int t = 0; t < LCH; t++) {
    float u = xp[(size_t)t * DMODEL] * rrmsL[t] * sc1;
    #pragma unroll
    for (int n = 0; n < NSTATE; n++) s[n] = fmaf(s[n], dA[n], u * dBz[n]);
  }
  #pragma unroll
  for (int n = 0; n < NSTATE; n++)
    s_fin[(((size_t)n * BATCH + b) * NCH + c) * DMODEL + d] = s[n];
}

// ---------------- scan pass2: serial chunk-carry combine (64 chunks) ----------------
__global__ void scan_pass2(const float* __restrict__ s_fin, const float* __restrict__ dAc_t,
                           float* __restrict__ s_in) {
  int idx = blockIdx.x * 256 + threadIdx.x;  // BATCH*DMODEL*NSTATE = 65536
  int d = idx & (DMODEL - 1);
  int b = (idx >> 10) & (BATCH - 1);
  int n = idx >> 12;
  float dc = dAc_t[n * DMODEL + d];
  float s = 0.f;
  for (int c = 0; c < NCH; c++) {
    size_t o = (((size_t)n * BATCH + b) * NCH + c) * DMODEL + d;
    s_in[o] = s;
    s = s_fin[o] + dc * s;
  }
}

// ======== fused3: scan pass3 (x2 = x + y + u*D) + rmsnorm2 (hb = bf16 normed) ========
// grid 256 = (b<<6)|c, 1024 threads. Phase0: rrms(x rows) -> LDS (2 rows/wave).
// Phase1: thread-d scan with carry-in, writes x2. __syncthreads publishes x2.
// Phase2: wave w rms-norms x2 rows w, w+16 (L2-hot) and writes hb.
__global__ void fused_scan3(const float* __restrict__ x, const float* __restrict__ scale1,
                            const float* __restrict__ scale2,
                            const float* __restrict__ dA_t, const float* __restrict__ dBz_t,
                            const float* __restrict__ Ct, const float* __restrict__ Dv,
                            const float* __restrict__ s_in,
                            float* __restrict__ out, ushort_t* __restrict__ hb) {
  const int b = blockIdx.x >> 6, c = blockIdx.x & 63;
  const int tid = threadIdx.x, wave = tid >> 6, lane = tid & 63;
  const size_t rowBase = (size_t)b * SEQLEN + (size_t)c * LCH;
  __shared__ float rrmsL[LCH];

  #pragma unroll
  for (int i = 0; i < 2; i++) {   // phase 0: rrms(x) rows wave, wave+16
    const int row = wave + 16 * i;
    const float4* p = (const float4*)(x + (rowBase + row) * DMODEL);
    float s = 0.f;
    #pragma unroll
    for (int w = 0; w < 4; w++) {
      float4 v = p[w * 64 + lane];
      s += v.x * v.x + v.y * v.y + v.z * v.z + v.w * v.w;
    }
    #pragma unroll
    for (int off = 32; off; off >>= 1) s += __shfl_xor(s, off, 64);
    if (lane == 0) rrmsL[row] = rsqrtf(s * (1.f / DMODEL) + 1e-6f);
  }
  __syncthreads();

  {   // phase 1: scan column d = tid, write x2
    const int d = tid;
    float dA[NSTATE], dBz[NSTATE], Cc[NSTATE], s[NSTATE];
    #pragma unroll
    for (int n = 0; n < NSTATE; n++) {
      dA[n] = dA_t[n * DMODEL + d];
      dBz[n] = dBz_t[n * DMODEL + d];
      Cc[n] = Ct[n * DMODEL + d];
      s[n] = s_in[(((size_t)n * BATCH + b) * NCH + c) * DMODEL + d];
    }
    const float sc1 = scale1[d], Dd = Dv[d];
    const float* xp = x + rowBase * DMODEL + d;
    float* op = out + rowBase * DMODEL + d;
    #pragma unroll 4
    for (int t = 0; t < LCH; t++) {
      float xv = xp[(size_t)t * DMODEL];
      float u = xv * rrmsL[t] * sc1;
      float y = 0.f;
      #pragma unroll
      for (int n = 0; n < NSTATE; n++) {
        s[n] = fmaf(s[n], dA[n], u * dBz[n]);
        y = fmaf(Cc[n], s[n], y);
      }
      op[(size_t)t * DMODEL] = xv + y + u * Dd;
    }
  }
  __syncthreads();   // compiler drains vmcnt before s_barrier -> x2 visible block-wide

  #pragma unroll
  for (int i = 0; i < 2; i++) {   // phase 2: rmsnorm2 of x2 rows wave, wave+16 -> hb
    const int row = wave + 16 * i;
    const float4* p = (const float4*)(out + (rowBase + row) * DMODEL);
    float4 v[4];
    float s = 0.f;
    #pragma unroll
    for (int w = 0; w < 4; w++) {
      v[w] = p[w * 64 + lane];
      s += v[w].x * v[w].x + v[w].y * v[w].y + v[w].z * v[w].z + v[w].w * v[w].w;
    }
    #pragma unroll
    for (int off = 32; off; off >>= 1) s += __shfl_xor(s, off, 64);
    float r = rsqrtf(s * (1.f / DMODEL) + 1e-6f);
    const float4* sc = (const float4*)scale2;
    ushort_t* hrow = hb + (rowBase + row) * DMODEL;
    #pragma unroll
    for (int w = 0; w < 4; w++) {
      float4 scv = sc[w * 64 + lane];
      ushort4 u;
      u.x = f2bf(v[w].x * r * scv.x);
      u.y = f2bf(v[w].y * r * scv.y);
      u.z = f2bf(v[w].z * r * scv.z);
      u.w = f2bf(v[w].w * r * scv.w);
      *(ushort4*)(hrow + (size_t)(w * 64 + lane) * 4) = u;
    }
  }
}

template <int N>
__device__ __forceinline__ void fence_vm() {
  asm volatile("s_waitcnt vmcnt(%0)" :: "n"(N) : "memory");
}

__device__ __forceinline__ void bar() { asm volatile("s_barrier" ::: "memory"); }

__device__ __forceinline__ void gl2lds16(const ushort_t* g, ushort_t* l) {
  __builtin_amdgcn_global_load_lds(
      (const __attribute__((address_space(1))) unsigned int*)g,
      (__attribute__((address_space(3))) unsigned int*)l, 16, 0, 0);
}

// ========== gemm1 (r12-verbatim): 256x256, BK=64, 2-slot, 16 waves, wave 64x64 ==========
template <int K>
__global__ __launch_bounds__(1024, 4) void gemm_w64(const ushort_t* __restrict__ A,
                                                    const ushort_t* __restrict__ B,
                                                    const float* __restrict__ bias,
                                                    ushort_t* __restrict__ outp,
                                                    int M, int N) {
  constexpr int SLOT = 32768;               // elems: A 256x64 + B 256x64 (64 KB)
  constexpr int NT = K / 64;
  __shared__ __align__(16) ushort_t lds[2 * SLOT];   // 128 KB

  const int tid = threadIdx.x;
  const int wave = tid >> 6, lane = tid & 63;
  const int wr = wave >> 2, wc = wave & 3;

  const int nwg = gridDim.x, cpx = nwg >> 3, bid = blockIdx.x;
  const int wg = (bid & 7) * cpx + (bid >> 3);
  const int nbn = N / 256;
  const int m0 = (wg / nbn) * 256, n0 = (wg % nbn) * 256;

  const int scol = 8 * ((tid & 7) ^ ((tid >> 3) & 7));
  const int wo = wave * 512;
  const ushort_t* aStg = A + (size_t)(m0 + (tid >> 3)) * K + scol;
  const ushort_t* aStg2 = aStg + (size_t)128 * K;
  const ushort_t* bStg = B + (size_t)(n0 + (tid >> 3)) * K + scol;
  const ushort_t* bStg2 = bStg + (size_t)128 * K;

  f32x4 acc[4][4] = {};

  {
    ushort_t* d = lds + wo;
    gl2lds16(aStg,  d);
    gl2lds16(aStg2, d + 8192);
    gl2lds16(bStg,  d + 16384);
    gl2lds16(bStg2, d + 24576);
    aStg += 64; aStg2 += 64; bStg += 64; bStg2 += 64;
  }
  fence_vm<0>(); bar();

  const int rl = lane & 15, c4 = lane >> 4;
  const int sw0 = (c4 ^ (rl & 7)) * 8;
  const int sw1 = ((4 | c4) ^ (rl & 7)) * 8;
  const int aOff = (wr * 64 + rl) * 64;
  const int bOff = 16384 + (wc * 64 + rl) * 64;

  const ushort_t* rSlot = lds;
  ushort_t*       wSlot = lds + SLOT;

  for (int t = 0; t < NT; ++t) {
    if (t + 1 < NT) {
      gl2lds16(aStg,  wSlot + wo);
      gl2lds16(aStg2, wSlot + 8192 + wo);
      gl2lds16(bStg,  wSlot + 16384 + wo);
      gl2lds16(bStg2, wSlot + 24576 + wo);
      aStg += 64; aStg2 += 64; bStg += 64; bStg2 += 64;
    }

    const ushort_t* ra0 = rSlot + aOff + sw0;
    const ushort_t* ra1 = rSlot + aOff + sw1;
    const ushort_t* rb0 = rSlot + bOff + sw0;
    const ushort_t* rb1 = rSlot + bOff + sw1;

    {
      short8 af[4], bf[4];
      #pragma unroll
      for (int m = 0; m < 4; m++) af[m] = *(const short8*)(ra0 + m * 1024);
      #pragma unroll
      for (int n = 0; n < 4; n++) bf[n] = *(const short8*)(rb0 + n * 1024);
      __builtin_amdgcn_s_setprio(1);
      #pragma unroll
      for (int m = 0; m < 4; m++)
        #pragma unroll
        for (int n = 0; n < 4; n++)
          acc[m][n] = __builtin_amdgcn_mfma_f32_16x16x32_bf16(af[m], bf[n], acc[m][n], 0, 0, 0);
      __builtin_amdgcn_s_setprio(0);
    }
    {
      short8 af[4], bf[4];
      #pragma unroll
      for (int m = 0; m < 4; m++) af[m] = *(const short8*)(ra1 + m * 1024);
      #pragma unroll
      for (int n = 0; n < 4; n++) bf[n] = *(const short8*)(rb1 + n * 1024);
      __builtin_amdgcn_s_setprio(1);
      #pragma unroll
      for (int m = 0; m < 4; m++)
        #pragma unroll
        for (int n = 0; n < 4; n++)
          acc[m][n] = __builtin_amdgcn_mfma_f32_16x16x32_bf16(af[m], bf[n], acc[m][n], 0, 0, 0);
      __builtin_amdgcn_s_setprio(0);
    }

    if (t + 1 < NT) { fence_vm<0>(); bar(); }
    const ushort_t* tmp = rSlot; rSlot = wSlot; wSlot = (ushort_t*)tmp;
  }

  const int colb = n0 + wc * 64 + rl;
  const int rowb = m0 + wr * 64 + c4 * 4;
  #pragma unroll
  for (int n = 0; n < 4; n++) {
    int col = colb + n * 16;
    float bs = bias[col];
    #pragma unroll
    for (int m = 0; m < 4; m++) {
      int row = rowb + m * 16;
      #pragma unroll
      for (int j = 0; j < 4; j++) {
        float v = acc[m][n][j] + bs;
        float g = v / (1.f + __expf(-1.702f * v));
        outp[(size_t)(row + j) * N + col] = f2bf(g);
      }
    }
  }
}

// ========== gemm2 (r12-verbatim): 256x128, BK=64, 3-slot, 16 waves, wave 64x32 ==========
template <int K, int MODE>
__global__ __launch_bounds__(1024, 4) void gemm16v(const ushort_t* __restrict__ A,
                                                   const ushort_t* __restrict__ B,
                                                   const float* __restrict__ bias,
                                                   const float* __restrict__ resid,
                                                   void* __restrict__ outp,
                                                   int M, int N) {
  constexpr int TILEA = 16384;
  constexpr int SLOT  = TILEA + 8192;
  constexpr int NT = K / 64;
  __shared__ __align__(16) ushort_t lds[3 * SLOT];   // 144 KB

  const int tid = threadIdx.x;
  const int wave = tid >> 6, lane = tid & 63;
  const int wr = wave >> 2, wc = wave & 3;

  const int nwg = gridDim.x, cpx = nwg >> 3, bid = blockIdx.x;
  const int wg = (bid & 7) * cpx + (bid >> 3);
  const int nbn = N / 128;
  const int m0 = (wg / nbn) * 256, n0 = (wg % nbn) * 128;

  const int scol = 8 * ((tid & 7) ^ ((tid >> 3) & 7));
  const int wo = wave * 512;

  const ushort_t* aStgLo = A + (size_t)(m0 + (tid >> 3)) * K + scol;
  const ushort_t* aStgHi = aStgLo + (size_t)128 * K;
  const ushort_t* bStg   = B + (size_t)(n0 + (tid >> 3)) * K + scol;

  f32x4 acc[4][2] = {};

  {
    ushort_t* s0p = lds;
    gl2lds16(aStgLo, s0p + wo);
    gl2lds16(aStgHi, s0p + 8192 + wo);
    gl2lds16(bStg,   s0p + TILEA + wo);
    ushort_t* s1p = lds + SLOT;
    gl2lds16(aStgLo + 64, s1p + wo);
    gl2lds16(aStgHi + 64, s1p + 8192 + wo);
    gl2lds16(bStg   + 64, s1p + TILEA + wo);
    aStgLo += 128; aStgHi += 128; bStg += 128;
  }
  fence_vm<3>(); bar();

  const int rl = lane & 15, c4 = lane >> 4;
  const int sw0 = (c4 ^ (rl & 7)) * 8;
  const int sw1 = ((4 | c4) ^ (rl & 7)) * 8;
  const int aOff = (wr * 64 + rl) * 64;
  const int bOff = TILEA + (wc * 32 + rl) * 64;

  const ushort_t* rSlot = lds;
  ushort_t*       wSlot = lds + 2 * SLOT;

  for (int t = 0; t < NT; ++t) {
    const ushort_t* ra0 = rSlot + aOff + sw0;
    const ushort_t* ra1 = rSlot + aOff + sw1;
    const ushort_t* rb0 = rSlot + bOff + sw0;
    const ushort_t* rb1 = rSlot + bOff + sw1;

    short8 af[2][4], bf[2][2];
    #pragma unroll
    for (int m = 0; m < 4; m++) {
      af[0][m] = *(const short8*)(ra0 + m * 1024);
      af[1][m] = *(const short8*)(ra1 + m * 1024);
    }
    #pragma unroll
    for (int n = 0; n < 2; n++) {
      bf[0][n] = *(const short8*)(rb0 + n * 1024);
      bf[1][n] = *(const short8*)(rb1 + n * 1024);
    }

    if (t + 2 < NT) {
      gl2lds16(aStgLo, wSlot + wo);
      gl2lds16(aStgHi, wSlot + 8192 + wo);
      gl2lds16(bStg,   wSlot + TILEA + wo);
      aStgLo += 64; aStgHi += 64; bStg += 64;
    }

    __builtin_amdgcn_s_setprio(1);
    #pragma unroll
    for (int kk = 0; kk < 2; kk++)
      #pragma unroll
      for (int m = 0; m < 4; m++)
        #pragma unroll
        for (int n = 0; n < 2; n++)
          acc[m][n] = __builtin_amdgcn_mfma_f32_16x16x32_bf16(af[kk][m], bf[kk][n],
                                                              acc[m][n], 0, 0, 0);
    __builtin_amdgcn_s_setprio(0);

    if (t + 2 < NT) fence_vm<3>();
    else            fence_vm<0>();
    bar();

    const ushort_t* rn = rSlot + SLOT;
    rSlot = (rn == lds + 3 * SLOT) ? lds : rn;
    ushort_t* wn = wSlot + SLOT;
    wSlot = (wn == lds + 3 * SLOT) ? lds : wn;
  }

  const int colb = n0 + wc * 32 + rl;
  const int rowb = m0 + wr * 64 + c4 * 4;
  #pragma unroll
  for (int n = 0; n < 2; n++) {
    int col = colb + n * 16;
    float bs = bias[col];
    #pragma unroll
    for (int m = 0; m < 4; m++) {
      int row = rowb + m * 16;
      #pragma unroll
      for (int j = 0; j < 4; j++) {
        float v = acc[m][n][j] + bs;
        size_t o = (size_t)(row + j) * N + col;
        if (MODE == 1) {
          float g = v / (1.f + __expf(-1.702f * v));
          ((ushort_t*)outp)[o] = f2bf(g);
        } else {
          ((float*)outp)[o] = resid[o] + v;
        }
      }
    }
  }
}

// ---------------- launch ----------------
extern "C" void kernel_launch(void* const* d_in, const int* in_sizes, int n_in,
                              void* d_out, int out_size, void* d_ws, size_t ws_size,
                              hipStream_t stream) {
  (void)in_sizes; (void)n_in; (void)out_size; (void)ws_size;
  const float* x      = (const float*)d_in[0];
  const float* A_ssm  = (const float*)d_in[1];
  const float* B_ssm  = (const float*)d_in[2];
  const float* C_ssm  = (const float*)d_in[3];
  const float* D_ssm  = (const float*)d_in[4];
  const float* scale1 = (const float*)d_in[5];
  const float* scale2 = (const float*)d_in[6];
  const float* w1     = (const float*)d_in[7];
  const float* b1     = (const float*)d_in[8];
  const float* w2     = (const float*)d_in[9];
  const float* b2     = (const float*)d_in[10];
  float* out = (float*)d_out;

  char* ws = (char*)d_ws;
  float*    dA_t  = (float*)(ws + 32768);                     // 64 KB
  float*    dBz_t = (float*)(ws + 98304);                     // 64 KB
  float*    dAc_t = (float*)(ws + 163840);                    // 64 KB
  float*    Ct    = (float*)(ws + 229376);                    // 64 KB
  ushort_t* hb    = (ushort_t*)(ws + 17072128);               // 16 MB
  ushort_t* w1t   = (ushort_t*)(ws + 33849344);               // 8 MB
  ushort_t* w2t   = (ushort_t*)(ws + 42237952);               // 8 MB
  ushort_t* gb    = (ushort_t*)(ws + 50626560);               // 64 MB
  // s_fin/s_in alias the gb region (dead before gemm1 writes gb)
  float*    s_fin = (float*)(ws + 50626560);                  // 16 MB
  float*    s_in  = (float*)(ws + 50626560 + 16777216);       // 16 MB

  const int ROWS = BATCH * SEQLEN;  // 8192

  coef_kernel<<<DMODEL / 256, 256, 0, stream>>>(A_ssm, B_ssm, C_ssm, dA_t, dBz_t, dAc_t, Ct);
  transpose_to_bf16<<<dim3(DFF / 32, DMODEL / 32), dim3(32, 8), 0, stream>>>(w1, w1t, DMODEL, DFF);
  transpose_to_bf16<<<dim3(DMODEL / 32, DFF / 32), dim3(32, 8), 0, stream>>>(w2, w2t, DFF, DMODEL);
  fused_scan1<<<BATCH * NCH, 1024, 0, stream>>>(x, scale1, dA_t, dBz_t, s_fin);
  scan_pass2<<<(BATCH * DMODEL * NSTATE) / 256, 256, 0, stream>>>(s_fin, dAc_t, s_in);
  fused_scan3<<<BATCH * NCH, 1024, 0, stream>>>(x, scale1, scale2, dA_t, dBz_t, Ct,
                                                D_ssm, s_in, out, hb);

  // gemm1: [8192x1024]@[1024x4096] -> gelu -> gb (bf16). 512 blocks, 256x256, BK=64.
  gemm_w64<DMODEL><<<(ROWS / 256) * (DFF / 256), 1024, 0, stream>>>(
      hb, w1t, b1, gb, ROWS, DFF);
  // gemm2: [8192x4096]@[4096x1024] + resid -> out (f32). 256 blocks, 256x128, BK=64.
  gemm16v<DFF, 2><<<(ROWS / 256) * (DMODEL / 128), 1024, 0, stream>>>(
      gb, w2t, b2, out, out, ROWS, DMODEL);
}

// Round 18
// 214.569 us; speedup vs baseline: 1.0382x; 1.0002x over previous
//
#include <hip/hip_runtime.h>
#include <cstdint>
#include <cstddef>

// Problem: x += ssm_scan(rmsnorm(x,s1)); out = x + gelu(rmsnorm(x,s2)@w1+b1)@w2+b2
// B=4 L=2048 D=1024 N=16 DFF=4096, f32 in/out. r12 smalls + gemm1(w64) + gemm2(128sq/8wps).

#define BATCH 4
#define SEQLEN 2048
#define DMODEL 1024
#define NSTATE 16
#define DFF 4096
#define NCH 32     // chunks over L
#define LCH 64     // SEQLEN / NCH

typedef unsigned short ushort_t;
typedef __attribute__((ext_vector_type(8))) short short8;
typedef __attribute__((ext_vector_type(4))) float f32x4;

__device__ __forceinline__ ushort_t f2bf(float f) {
  uint32_t u = __builtin_bit_cast(uint32_t, f);
  uint32_t r = (u + 0x7FFFu + ((u >> 16) & 1u)) >> 16;
  return (ushort_t)r;
}

// ---------------- coefficient precompute ----------------
__global__ void coef_kernel(const float* __restrict__ A_ssm, const float* __restrict__ B_ssm,
                            const float* __restrict__ C_ssm,
                            float* __restrict__ dA_t, float* __restrict__ dBz_t,
                            float* __restrict__ dAc_t, float* __restrict__ Ct) {
  int d = blockIdx.x * 256 + threadIdx.x;
  if (d >= DMODEL) return;
  const float l0 = -6.907755278982137f;       // log(0.001)
  const float ld = 0.30701134573253947f;      // log(100)/15
  for (int n = 0; n < NSTATE; n++) {
    float dt = expf(l0 + (float)n * ld);
    float a  = A_ssm[d * NSTATE + n];
    float ea = expf(a);
    float da = expf(-ea * dt);
    float dbz = B_ssm[d * NSTATE + n] * (1.f - da) / ea;
    float dac = expf(-ea * dt * (float)LCH);
    dA_t [n * DMODEL + d] = da;
    dBz_t[n * DMODEL + d] = dbz;
    dAc_t[n * DMODEL + d] = dac;
    Ct   [n * DMODEL + d] = C_ssm[d * NSTATE + n];
  }
}

// ---------------- transpose f32 [R][C] -> bf16 [C][R] ----------------
__global__ void transpose_to_bf16(const float* __restrict__ src, ushort_t* __restrict__ dst,
                                  int R, int C) {
  __shared__ float tile[32][33];
  int bx = blockIdx.x * 32, by = blockIdx.y * 32;
  int tx = threadIdx.x, ty = threadIdx.y;
  #pragma unroll
  for (int i = 0; i < 4; i++) {
    int r = by + ty + i * 8;
    tile[ty + i * 8][tx] = src[(size_t)r * C + bx + tx];
  }
  __syncthreads();
  #pragma unroll
  for (int i = 0; i < 4; i++) {
    int c = bx + ty + i * 8;
    dst[(size_t)c * R + by + tx] = f2bf(tile[tx][ty + i * 8]);
  }
}

// ---------------- rmsnorm pass 1: rrms per row ----------------
__global__ void rms1_kernel(const float* __restrict__ x, float* __restrict__ rrms) {
  int row = blockIdx.x * 4 + (threadIdx.x >> 6);
  int lane = threadIdx.x & 63;
  const float4* p = (const float4*)(x + (size_t)row * DMODEL);
  float s = 0.f;
  #pragma unroll
  for (int w = 0; w < 4; w++) {
    float4 v = p[w * 64 + lane];
    s += v.x * v.x + v.y * v.y + v.z * v.z + v.w * v.w;
  }
  #pragma unroll
  for (int off = 32; off; off >>= 1) s += __shfl_xor(s, off, 64);
  if (lane == 0) rrms[row] = rsqrtf(s * (1.f / DMODEL) + 1e-6f);
}

// ---------------- scan pass1: per-chunk local final states ----------------
__global__ void scan_pass1(const float* __restrict__ x, const float* __restrict__ rrms,
                           const float* __restrict__ scale1,
                           const float* __restrict__ dA_t, const float* __restrict__ dBz_t,
                           float* __restrict__ s_fin) {
  int d = blockIdx.x * 256 + threadIdx.x;
  int b = blockIdx.y, c = blockIdx.z;
  float dA[NSTATE], dBz[NSTATE], s[NSTATE];
  #pragma unroll
  for (int n = 0; n < NSTATE; n++) {
    dA[n] = dA_t[n * DMODEL + d];
    dBz[n] = dBz_t[n * DMODEL + d];
    s[n] = 0.f;
  }
  float sc1 = scale1[d];
  const float* xp = x + ((size_t)b * SEQLEN + (size_t)c * LCH) * DMODEL + d;
  const float* rp = rrms + b * SEQLEN + c * LCH;
  for (int t = 0; t < LCH; t++) {
    float u = xp[(size_t)t * DMODEL] * rp[t] * sc1;
    #pragma unroll
    for (int n = 0; n < NSTATE; n++) s[n] = fmaf(s[n], dA[n], u * dBz[n]);
  }
  #pragma unroll
  for (int n = 0; n < NSTATE; n++)
    s_fin[(((size_t)n * BATCH + b) * NCH + c) * DMODEL + d] = s[n];
}

// ---------------- scan pass2: serial chunk-carry combine ----------------
__global__ void scan_pass2(const float* __restrict__ s_fin, const float* __restrict__ dAc_t,
                           float* __restrict__ s_in) {
  int idx = blockIdx.x * 256 + threadIdx.x;  // BATCH*DMODEL*NSTATE = 65536
  int d = idx & (DMODEL - 1);
  int b = (idx >> 10) & (BATCH - 1);
  int n = idx >> 12;
  float dc = dAc_t[n * DMODEL + d];
  float s = 0.f;
  for (int c = 0; c < NCH; c++) {
    size_t o = (((size_t)n * BATCH + b) * NCH + c) * DMODEL + d;
    s_in[o] = s;
    s = s_fin[o] + dc * s;
  }
}

// ---------------- scan pass3: full scan with carry-in, write x2 = x + y + u*D ----------------
__global__ void scan_pass3(const float* __restrict__ x, const float* __restrict__ rrms,
                           const float* __restrict__ scale1,
                           const float* __restrict__ dA_t, const float* __restrict__ dBz_t,
                           const float* __restrict__ Ct, const float* __restrict__ Dv,
                           const float* __restrict__ s_in, float* __restrict__ out) {
  int d = blockIdx.x * 256 + threadIdx.x;
  int b = blockIdx.y, c = blockIdx.z;
  float dA[NSTATE], dBz[NSTATE], Cc[NSTATE], s[NSTATE];
  #pragma unroll
  for (int n = 0; n < NSTATE; n++) {
    dA[n] = dA_t[n * DMODEL + d];
    dBz[n] = dBz_t[n * DMODEL + d];
    Cc[n] = Ct[n * DMODEL + d];
    s[n] = s_in[(((size_t)n * BATCH + b) * NCH + c) * DMODEL + d];
  }
  float sc1 = scale1[d], Dd = Dv[d];
  const float* xp = x + ((size_t)b * SEQLEN + (size_t)c * LCH) * DMODEL + d;
  const float* rp = rrms + b * SEQLEN + c * LCH;
  float* op = out + ((size_t)b * SEQLEN + (size_t)c * LCH) * DMODEL + d;
  for (int t = 0; t < LCH; t++) {
    float xv = xp[(size_t)t * DMODEL];
    float u = xv * rp[t] * sc1;
    float y = 0.f;
    #pragma unroll
    for (int n = 0; n < NSTATE; n++) {
      s[n] = fmaf(s[n], dA[n], u * dBz[n]);
      y = fmaf(Cc[n], s[n], y);
    }
    op[(size_t)t * DMODEL] = xv + y + u * Dd;
  }
}

// ---------------- rmsnorm2: x2 -> bf16 normalized ----------------
__global__ void rms2_kernel(const float* __restrict__ x2, const float* __restrict__ scale2,
                            ushort_t* __restrict__ hb) {
  int row = blockIdx.x * 4 + (threadIdx.x >> 6);
  int lane = threadIdx.x & 63;
  const float4* p = (const float4*)(x2 + (size_t)row * DMODEL);
  float4 v[4];
  float s = 0.f;
  #pragma unroll
  for (int w = 0; w < 4; w++) {
    v[w] = p[w * 64 + lane];
    s += v[w].x * v[w].x + v[w].y * v[w].y + v[w].z * v[w].z + v[w].w * v[w].w;
  }
  #pragma unroll
  for (int off = 32; off; off >>= 1) s += __shfl_xor(s, off, 64);
  float r = rsqrtf(s * (1.f / DMODEL) + 1e-6f);
  const float4* sc = (const float4*)scale2;
  #pragma unroll
  for (int w = 0; w < 4; w++) {
    float4 scv = sc[w * 64 + lane];
    ushort4 u;
    u.x = f2bf(v[w].x * r * scv.x);
    u.y = f2bf(v[w].y * r * scv.y);
    u.z = f2bf(v[w].z * r * scv.z);
    u.w = f2bf(v[w].w * r * scv.w);
    *(ushort4*)(hb + (size_t)row * DMODEL + (size_t)(w * 64 + lane) * 4) = u;
  }
}

template <int N>
__device__ __forceinline__ void fence_vm() {
  asm volatile("s_waitcnt vmcnt(%0)" :: "n"(N) : "memory");
}

__device__ __forceinline__ void bar() { asm volatile("s_barrier" ::: "memory"); }

__device__ __forceinline__ void gl2lds16(const ushort_t* g, ushort_t* l) {
  __builtin_amdgcn_global_load_lds(
      (const __attribute__((address_space(1))) unsigned int*)g,
      (__attribute__((address_space(3))) unsigned int*)l, 16, 0, 0);
}

// ========== gemm1 (r12-verbatim): 256x256, BK=64, 2-slot, 16 waves, wave 64x64 ==========
template <int K>
__global__ __launch_bounds__(1024, 4) void gemm_w64(const ushort_t* __restrict__ A,
                                                    const ushort_t* __restrict__ B,
                                                    const float* __restrict__ bias,
                                                    ushort_t* __restrict__ outp,
                                                    int M, int N) {
  constexpr int SLOT = 32768;               // elems: A 256x64 + B 256x64 (64 KB)
  constexpr int NT = K / 64;
  __shared__ __align__(16) ushort_t lds[2 * SLOT];   // 128 KB

  const int tid = threadIdx.x;
  const int wave = tid >> 6, lane = tid & 63;
  const int wr = wave >> 2, wc = wave & 3;

  const int nwg = gridDim.x, cpx = nwg >> 3, bid = blockIdx.x;
  const int wg = (bid & 7) * cpx + (bid >> 3);
  const int nbn = N / 256;
  const int m0 = (wg / nbn) * 256, n0 = (wg % nbn) * 256;

  const int scol = 8 * ((tid & 7) ^ ((tid >> 3) & 7));
  const int wo = wave * 512;
  const ushort_t* aStg = A + (size_t)(m0 + (tid >> 3)) * K + scol;
  const ushort_t* aStg2 = aStg + (size_t)128 * K;
  const ushort_t* bStg = B + (size_t)(n0 + (tid >> 3)) * K + scol;
  const ushort_t* bStg2 = bStg + (size_t)128 * K;

  f32x4 acc[4][4] = {};

  {
    ushort_t* d = lds + wo;
    gl2lds16(aStg,  d);
    gl2lds16(aStg2, d + 8192);
    gl2lds16(bStg,  d + 16384);
    gl2lds16(bStg2, d + 24576);
    aStg += 64; aStg2 += 64; bStg += 64; bStg2 += 64;
  }
  fence_vm<0>(); bar();

  const int rl = lane & 15, c4 = lane >> 4;
  const int sw0 = (c4 ^ (rl & 7)) * 8;
  const int sw1 = ((4 | c4) ^ (rl & 7)) * 8;
  const int aOff = (wr * 64 + rl) * 64;
  const int bOff = 16384 + (wc * 64 + rl) * 64;

  const ushort_t* rSlot = lds;
  ushort_t*       wSlot = lds + SLOT;

  for (int t = 0; t < NT; ++t) {
    if (t + 1 < NT) {
      gl2lds16(aStg,  wSlot + wo);
      gl2lds16(aStg2, wSlot + 8192 + wo);
      gl2lds16(bStg,  wSlot + 16384 + wo);
      gl2lds16(bStg2, wSlot + 24576 + wo);
      aStg += 64; aStg2 += 64; bStg += 64; bStg2 += 64;
    }

    const ushort_t* ra0 = rSlot + aOff + sw0;
    const ushort_t* ra1 = rSlot + aOff + sw1;
    const ushort_t* rb0 = rSlot + bOff + sw0;
    const ushort_t* rb1 = rSlot + bOff + sw1;

    {
      short8 af[4], bf[4];
      #pragma unroll
      for (int m = 0; m < 4; m++) af[m] = *(const short8*)(ra0 + m * 1024);
      #pragma unroll
      for (int n = 0; n < 4; n++) bf[n] = *(const short8*)(rb0 + n * 1024);
      __builtin_amdgcn_s_setprio(1);
      #pragma unroll
      for (int m = 0; m < 4; m++)
        #pragma unroll
        for (int n = 0; n < 4; n++)
          acc[m][n] = __builtin_amdgcn_mfma_f32_16x16x32_bf16(af[m], bf[n], acc[m][n], 0, 0, 0);
      __builtin_amdgcn_s_setprio(0);
    }
    {
      short8 af[4], bf[4];
      #pragma unroll
      for (int m = 0; m < 4; m++) af[m] = *(const short8*)(ra1 + m * 1024);
      #pragma unroll
      for (int n = 0; n < 4; n++) bf[n] = *(const short8*)(rb1 + n * 1024);
      __builtin_amdgcn_s_setprio(1);
      #pragma unroll
      for (int m = 0; m < 4; m++)
        #pragma unroll
        for (int n = 0; n < 4; n++)
          acc[m][n] = __builtin_amdgcn_mfma_f32_16x16x32_bf16(af[m], bf[n], acc[m][n], 0, 0, 0);
      __builtin_amdgcn_s_setprio(0);
    }

    if (t + 1 < NT) { fence_vm<0>(); bar(); }
    const ushort_t* tmp = rSlot; rSlot = wSlot; wSlot = (ushort_t*)tmp;
  }

  const int colb = n0 + wc * 64 + rl;
  const int rowb = m0 + wr * 64 + c4 * 4;
  #pragma unroll
  for (int n = 0; n < 4; n++) {
    int col = colb + n * 16;
    float bs = bias[col];
    #pragma unroll
    for (int m = 0; m < 4; m++) {
      int row = rowb + m * 16;
      #pragma unroll
      for (int j = 0; j < 4; j++) {
        float v = acc[m][n][j] + bs;
        float g = v / (1.f + __expf(-1.702f * v));
        outp[(size_t)(row + j) * N + col] = f2bf(g);
      }
    }
  }
}

// ========== gemm2: 128x128, BK=64, 2-slot (64 KB), 1024 thr, wave 32x32, 8 waves/SIMD ====
// r14-proven structure (hits the LDS floor, 1612cy/block-tile, 74% occupancy) applied to
// gemm2's shape. Unlike r14's gemm1, gemm2's FETCH does not grow vs 256x128 (A panel
// shared across only 8 n-blocks, L2-hot with XCD-contiguous swizzle).
template <int K>
__global__ __launch_bounds__(1024, 8) void gemm2_128(const ushort_t* __restrict__ A,
                                                     const ushort_t* __restrict__ B,
                                                     const float* __restrict__ bias,
                                                     const float* __restrict__ resid,
                                                     float* __restrict__ outp,
                                                     int M, int N) {
  constexpr int SLOT = 16384;               // elems: A 128x64 + B 128x64 (32 KB)
  constexpr int NT = K / 64;
  __shared__ __align__(16) ushort_t lds[2 * SLOT];   // 64 KB

  const int tid = threadIdx.x;
  const int wave = tid >> 6, lane = tid & 63;
  const int wr = wave >> 2, wc = wave & 3;  // 4 x 4 waves, 32x32 each

  const int nwg = gridDim.x, cpx = nwg >> 3, bid = blockIdx.x;
  const int wg = (bid & 7) * cpx + (bid >> 3);
  const int nbn = N / 128;
  const int m0 = (wg / nbn) * 128, n0 = (wg % nbn) * 128;

  // staging: row = tid>>3 (0..127), chunk = tid&7, BK=64 swizzle (src pre-swizzled)
  const int scol = 8 * ((tid & 7) ^ ((tid >> 3) & 7));
  const int wo = wave * 512;
  const ushort_t* aStg = A + (size_t)(m0 + (tid >> 3)) * K + scol;
  const ushort_t* bStg = B + (size_t)(n0 + (tid >> 3)) * K + scol;

  f32x4 acc[2][2] = {};

  gl2lds16(aStg, lds + wo);
  gl2lds16(bStg, lds + 8192 + wo);
  aStg += 64; bStg += 64;
  fence_vm<0>(); bar();

  const int rl = lane & 15, c4 = lane >> 4;
  const int sw0 = (c4 ^ (rl & 7)) * 8;           // kk=0 read swizzle (BK=64 pattern)
  const int sw1 = ((4 | c4) ^ (rl & 7)) * 8;     // kk=1
  const int aOff = (wr * 32 + rl) * 64;
  const int bOff = 8192 + (wc * 32 + rl) * 64;

  const ushort_t* rSlot = lds;
  ushort_t*       wSlot = lds + SLOT;

  for (int t = 0; t < NT; ++t) {
    if (t + 1 < NT) {                       // stage t+1 at top (hides under compute)
      gl2lds16(aStg, wSlot + wo);
      gl2lds16(bStg, wSlot + 8192 + wo);
      aStg += 64; bStg += 64;
    }

    {   // kk = 0
      short8 af[2], bf[2];
      af[0] = *(const short8*)(rSlot + aOff + sw0);
      af[1] = *(const short8*)(rSlot + aOff + sw0 + 1024);
      bf[0] = *(const short8*)(rSlot + bOff + sw0);
      bf[1] = *(const short8*)(rSlot + bOff + sw0 + 1024);
      __builtin_amdgcn_s_setprio(1);
      #pragma unroll
      for (int m = 0; m < 2; m++)
        #pragma unroll
        for (int n = 0; n < 2; n++)
          acc[m][n] = __builtin_amdgcn_mfma_f32_16x16x32_bf16(af[m], bf[n], acc[m][n], 0, 0, 0);
      __builtin_amdgcn_s_setprio(0);
    }
    {   // kk = 1
      short8 af[2], bf[2];
      af[0] = *(const short8*)(rSlot + aOff + sw1);
      af[1] = *(const short8*)(rSlot + aOff + sw1 + 1024);
      bf[0] = *(const short8*)(rSlot + bOff + sw1);
      bf[1] = *(const short8*)(rSlot + bOff + sw1 + 1024);
      __builtin_amdgcn_s_setprio(1);
      #pragma unroll
      for (int m = 0; m < 2; m++)
        #pragma unroll
        for (int n = 0; n < 2; n++)
          acc[m][n] = __builtin_amdgcn_mfma_f32_16x16x32_bf16(af[m], bf[n], acc[m][n], 0, 0, 0);
      __builtin_amdgcn_s_setprio(0);
    }

    if (t + 1 < NT) { fence_vm<0>(); bar(); }
    const ushort_t* tmp = rSlot; rSlot = wSlot; wSlot = (ushort_t*)tmp;
  }

  // epilogue: out = resid + acc + bias (f32)
  const int colb = n0 + wc * 32 + rl;
  const int rowb = m0 + wr * 32 + c4 * 4;
  #pragma unroll
  for (int n = 0; n < 2; n++) {
    int col = colb + n * 16;
    float bs = bias[col];
    #pragma unroll
    for (int m = 0; m < 2; m++) {
      int row = rowb + m * 16;
      #pragma unroll
      for (int j = 0; j < 4; j++) {
        size_t o = (size_t)(row + j) * N + col;
        outp[o] = resid[o] + acc[m][n][j] + bs;
      }
    }
  }
}

// ---------------- launch ----------------
extern "C" void kernel_launch(void* const* d_in, const int* in_sizes, int n_in,
                              void* d_out, int out_size, void* d_ws, size_t ws_size,
                              hipStream_t stream) {
  (void)in_sizes; (void)n_in; (void)out_size; (void)ws_size;
  const float* x      = (const float*)d_in[0];
  const float* A_ssm  = (const float*)d_in[1];
  const float* B_ssm  = (const float*)d_in[2];
  const float* C_ssm  = (const float*)d_in[3];
  const float* D_ssm  = (const float*)d_in[4];
  const float* scale1 = (const float*)d_in[5];
  const float* scale2 = (const float*)d_in[6];
  const float* w1     = (const float*)d_in[7];
  const float* b1     = (const float*)d_in[8];
  const float* w2     = (const float*)d_in[9];
  const float* b2     = (const float*)d_in[10];
  float* out = (float*)d_out;

  char* ws = (char*)d_ws;
  float*    rrms  = (float*)(ws + 0);                         // 32 KB
  float*    dA_t  = (float*)(ws + 32768);                     // 64 KB
  float*    dBz_t = (float*)(ws + 98304);                     // 64 KB
  float*    dAc_t = (float*)(ws + 163840);                    // 64 KB
  float*    Ct    = (float*)(ws + 229376);                    // 64 KB
  float*    s_fin = (float*)(ws + 294912);                    // 8 MB
  float*    s_in  = (float*)(ws + 8683520);                   // 8 MB
  ushort_t* hb    = (ushort_t*)(ws + 17072128);               // 16 MB
  ushort_t* w1t   = (ushort_t*)(ws + 33849344);               // 8 MB
  ushort_t* w2t   = (ushort_t*)(ws + 42237952);               // 8 MB
  ushort_t* gb    = (ushort_t*)(ws + 50626560);               // 64 MB

  const int ROWS = BATCH * SEQLEN;  // 8192

  coef_kernel<<<DMODEL / 256, 256, 0, stream>>>(A_ssm, B_ssm, C_ssm, dA_t, dBz_t, dAc_t, Ct);
  transpose_to_bf16<<<dim3(DFF / 32, DMODEL / 32), dim3(32, 8), 0, stream>>>(w1, w1t, DMODEL, DFF);
  transpose_to_bf16<<<dim3(DMODEL / 32, DFF / 32), dim3(32, 8), 0, stream>>>(w2, w2t, DFF, DMODEL);
  rms1_kernel<<<ROWS / 4, 256, 0, stream>>>(x, rrms);
  scan_pass1<<<dim3(DMODEL / 256, BATCH, NCH), 256, 0, stream>>>(x, rrms, scale1, dA_t, dBz_t, s_fin);
  scan_pass2<<<(BATCH * DMODEL * NSTATE) / 256, 256, 0, stream>>>(s_fin, dAc_t, s_in);
  scan_pass3<<<dim3(DMODEL / 256, BATCH, NCH), 256, 0, stream>>>(x, rrms, scale1, dA_t, dBz_t, Ct,
                                                                 D_ssm, s_in, out);
  rms2_kernel<<<ROWS / 4, 256, 0, stream>>>(out, scale2, hb);

  // gemm1: [8192x1024]@[1024x4096] -> gelu -> gb (bf16). 512 blocks, 256x256, BK=64.
  gemm_w64<DMODEL><<<(ROWS / 256) * (DFF / 256), 1024, 0, stream>>>(
      hb, w1t, b1, gb, ROWS, DFF);
  // gemm2: [8192x4096]@[4096x1024] + resid -> out (f32). 512 blocks, 128x128, 8 w/SIMD.
  gemm2_128<DFF><<<(ROWS / 128) * (DMODEL / 128), 1024, 0, stream>>>(
      gb, w2t, b2, out, out, ROWS, DMODEL);
}

// Round 19
// 211.314 us; speedup vs baseline: 1.0542x; 1.0154x over previous
//
#include <hip/hip_runtime.h>
#include <cstdint>
#include <cstddef>

// Problem: x += ssm_scan(rmsnorm(x,s1)); out = x + gelu(rmsnorm(x,s2)@w1+b1)@w2+b2
// B=4 L=2048 D=1024 N=16 DFF=4096, f32 in/out. bf16 MFMA GEMMs. (r12 best config, locked.)

#define BATCH 4
#define SEQLEN 2048
#define DMODEL 1024
#define NSTATE 16
#define DFF 4096
#define NCH 32     // chunks over L
#define LCH 64     // SEQLEN / NCH

typedef unsigned short ushort_t;
typedef __attribute__((ext_vector_type(8))) short short8;
typedef __attribute__((ext_vector_type(4))) float f32x4;

__device__ __forceinline__ ushort_t f2bf(float f) {
  uint32_t u = __builtin_bit_cast(uint32_t, f);
  uint32_t r = (u + 0x7FFFu + ((u >> 16) & 1u)) >> 16;
  return (ushort_t)r;
}

// ---------------- coefficient precompute ----------------
__global__ void coef_kernel(const float* __restrict__ A_ssm, const float* __restrict__ B_ssm,
                            const float* __restrict__ C_ssm,
                            float* __restrict__ dA_t, float* __restrict__ dBz_t,
                            float* __restrict__ dAc_t, float* __restrict__ Ct) {
  int d = blockIdx.x * 256 + threadIdx.x;
  if (d >= DMODEL) return;
  const float l0 = -6.907755278982137f;       // log(0.001)
  const float ld = 0.30701134573253947f;      // log(100)/15
  for (int n = 0; n < NSTATE; n++) {
    float dt = expf(l0 + (float)n * ld);
    float a  = A_ssm[d * NSTATE + n];
    float ea = expf(a);
    float da = expf(-ea * dt);
    float dbz = B_ssm[d * NSTATE + n] * (1.f - da) / ea;
    float dac = expf(-ea * dt * (float)LCH);
    dA_t [n * DMODEL + d] = da;
    dBz_t[n * DMODEL + d] = dbz;
    dAc_t[n * DMODEL + d] = dac;
    Ct   [n * DMODEL + d] = C_ssm[d * NSTATE + n];
  }
}

// ---------------- transpose f32 [R][C] -> bf16 [C][R] ----------------
__global__ void transpose_to_bf16(const float* __restrict__ src, ushort_t* __restrict__ dst,
                                  int R, int C) {
  __shared__ float tile[32][33];
  int bx = blockIdx.x * 32, by = blockIdx.y * 32;
  int tx = threadIdx.x, ty = threadIdx.y;
  #pragma unroll
  for (int i = 0; i < 4; i++) {
    int r = by + ty + i * 8;
    tile[ty + i * 8][tx] = src[(size_t)r * C + bx + tx];
  }
  __syncthreads();
  #pragma unroll
  for (int i = 0; i < 4; i++) {
    int c = bx + ty + i * 8;
    dst[(size_t)c * R + by + tx] = f2bf(tile[tx][ty + i * 8]);
  }
}

// ---------------- rmsnorm pass 1: rrms per row ----------------
__global__ void rms1_kernel(const float* __restrict__ x, float* __restrict__ rrms) {
  int row = blockIdx.x * 4 + (threadIdx.x >> 6);
  int lane = threadIdx.x & 63;
  const float4* p = (const float4*)(x + (size_t)row * DMODEL);
  float s = 0.f;
  #pragma unroll
  for (int w = 0; w < 4; w++) {
    float4 v = p[w * 64 + lane];
    s += v.x * v.x + v.y * v.y + v.z * v.z + v.w * v.w;
  }
  #pragma unroll
  for (int off = 32; off; off >>= 1) s += __shfl_xor(s, off, 64);
  if (lane == 0) rrms[row] = rsqrtf(s * (1.f / DMODEL) + 1e-6f);
}

// ---------------- scan pass1: per-chunk local final states ----------------
__global__ void scan_pass1(const float* __restrict__ x, const float* __restrict__ rrms,
                           const float* __restrict__ scale1,
                           const float* __restrict__ dA_t, const float* __restrict__ dBz_t,
                           float* __restrict__ s_fin) {
  int d = blockIdx.x * 256 + threadIdx.x;
  int b = blockIdx.y, c = blockIdx.z;
  float dA[NSTATE], dBz[NSTATE], s[NSTATE];
  #pragma unroll
  for (int n = 0; n < NSTATE; n++) {
    dA[n] = dA_t[n * DMODEL + d];
    dBz[n] = dBz_t[n * DMODEL + d];
    s[n] = 0.f;
  }
  float sc1 = scale1[d];
  const float* xp = x + ((size_t)b * SEQLEN + (size_t)c * LCH) * DMODEL + d;
  const float* rp = rrms + b * SEQLEN + c * LCH;
  for (int t = 0; t < LCH; t++) {
    float u = xp[(size_t)t * DMODEL] * rp[t] * sc1;
    #pragma unroll
    for (int n = 0; n < NSTATE; n++) s[n] = fmaf(s[n], dA[n], u * dBz[n]);
  }
  #pragma unroll
  for (int n = 0; n < NSTATE; n++)
    s_fin[(((size_t)n * BATCH + b) * NCH + c) * DMODEL + d] = s[n];
}

// ---------------- scan pass2: serial chunk-carry combine ----------------
__global__ void scan_pass2(const float* __restrict__ s_fin, const float* __restrict__ dAc_t,
                           float* __restrict__ s_in) {
  int idx = blockIdx.x * 256 + threadIdx.x;  // BATCH*DMODEL*NSTATE = 65536
  int d = idx & (DMODEL - 1);
  int b = (idx >> 10) & (BATCH - 1);
  int n = idx >> 12;
  float dc = dAc_t[n * DMODEL + d];
  float s = 0.f;
  for (int c = 0; c < NCH; c++) {
    size_t o = (((size_t)n * BATCH + b) * NCH + c) * DMODEL + d;
    s_in[o] = s;
    s = s_fin[o] + dc * s;
  }
}

// ---------------- scan pass3: full scan with carry-in, write x2 = x + y + u*D ----------------
__global__ void scan_pass3(const float* __restrict__ x, const float* __restrict__ rrms,
                           const float* __restrict__ scale1,
                           const float* __restrict__ dA_t, const float* __restrict__ dBz_t,
                           const float* __restrict__ Ct, const float* __restrict__ Dv,
                           const float* __restrict__ s_in, float* __restrict__ out) {
  int d = blockIdx.x * 256 + threadIdx.x;
  int b = blockIdx.y, c = blockIdx.z;
  float dA[NSTATE], dBz[NSTATE], Cc[NSTATE], s[NSTATE];
  #pragma unroll
  for (int n = 0; n < NSTATE; n++) {
    dA[n] = dA_t[n * DMODEL + d];
    dBz[n] = dBz_t[n * DMODEL + d];
    Cc[n] = Ct[n * DMODEL + d];
    s[n] = s_in[(((size_t)n * BATCH + b) * NCH + c) * DMODEL + d];
  }
  float sc1 = scale1[d], Dd = Dv[d];
  const float* xp = x + ((size_t)b * SEQLEN + (size_t)c * LCH) * DMODEL + d;
  const float* rp = rrms + b * SEQLEN + c * LCH;
  float* op = out + ((size_t)b * SEQLEN + (size_t)c * LCH) * DMODEL + d;
  for (int t = 0; t < LCH; t++) {
    float xv = xp[(size_t)t * DMODEL];
    float u = xv * rp[t] * sc1;
    float y = 0.f;
    #pragma unroll
    for (int n = 0; n < NSTATE; n++) {
      s[n] = fmaf(s[n], dA[n], u * dBz[n]);
      y = fmaf(Cc[n], s[n], y);
    }
    op[(size_t)t * DMODEL] = xv + y + u * Dd;
  }
}

// ---------------- rmsnorm2: x2 -> bf16 normalized ----------------
__global__ void rms2_kernel(const float* __restrict__ x2, const float* __restrict__ scale2,
                            ushort_t* __restrict__ hb) {
  int row = blockIdx.x * 4 + (threadIdx.x >> 6);
  int lane = threadIdx.x & 63;
  const float4* p = (const float4*)(x2 + (size_t)row * DMODEL);
  float4 v[4];
  float s = 0.f;
  #pragma unroll
  for (int w = 0; w < 4; w++) {
    v[w] = p[w * 64 + lane];
    s += v[w].x * v[w].x + v[w].y * v[w].y + v[w].z * v[w].z + v[w].w * v[w].w;
  }
  #pragma unroll
  for (int off = 32; off; off >>= 1) s += __shfl_xor(s, off, 64);
  float r = rsqrtf(s * (1.f / DMODEL) + 1e-6f);
  const float4* sc = (const float4*)scale2;
  #pragma unroll
  for (int w = 0; w < 4; w++) {
    float4 scv = sc[w * 64 + lane];
    ushort4 u;
    u.x = f2bf(v[w].x * r * scv.x);
    u.y = f2bf(v[w].y * r * scv.y);
    u.z = f2bf(v[w].z * r * scv.z);
    u.w = f2bf(v[w].w * r * scv.w);
    *(ushort4*)(hb + (size_t)row * DMODEL + (size_t)(w * 64 + lane) * 4) = u;
  }
}

template <int N>
__device__ __forceinline__ void fence_vm() {
  asm volatile("s_waitcnt vmcnt(%0)" :: "n"(N) : "memory");
}

__device__ __forceinline__ void bar() { asm volatile("s_barrier" ::: "memory"); }

__device__ __forceinline__ void gl2lds16(const ushort_t* g, ushort_t* l) {
  __builtin_amdgcn_global_load_lds(
      (const __attribute__((address_space(1))) unsigned int*)g,
      (__attribute__((address_space(3))) unsigned int*)l, 16, 0, 0);
}

// ========== gemm1: 256x256, BK=64, 2-slot (128 KB), 16 waves, wave tile 64x64 ==========
template <int K>
__global__ __launch_bounds__(1024, 4) void gemm_w64(const ushort_t* __restrict__ A,
                                                    const ushort_t* __restrict__ B,
                                                    const float* __restrict__ bias,
                                                    ushort_t* __restrict__ outp,
                                                    int M, int N) {
  constexpr int SLOT = 32768;               // elems: A 256x64 + B 256x64 (64 KB)
  constexpr int NT = K / 64;
  __shared__ __align__(16) ushort_t lds[2 * SLOT];   // 128 KB

  const int tid = threadIdx.x;
  const int wave = tid >> 6, lane = tid & 63;
  const int wr = wave >> 2, wc = wave & 3;

  const int nwg = gridDim.x, cpx = nwg >> 3, bid = blockIdx.x;
  const int wg = (bid & 7) * cpx + (bid >> 3);
  const int nbn = N / 256;
  const int m0 = (wg / nbn) * 256, n0 = (wg % nbn) * 256;

  const int scol = 8 * ((tid & 7) ^ ((tid >> 3) & 7));
  const int wo = wave * 512;
  const ushort_t* aStg = A + (size_t)(m0 + (tid >> 3)) * K + scol;
  const ushort_t* aStg2 = aStg + (size_t)128 * K;
  const ushort_t* bStg = B + (size_t)(n0 + (tid >> 3)) * K + scol;
  const ushort_t* bStg2 = bStg + (size_t)128 * K;

  f32x4 acc[4][4] = {};

  {
    ushort_t* d = lds + wo;
    gl2lds16(aStg,  d);
    gl2lds16(aStg2, d + 8192);
    gl2lds16(bStg,  d + 16384);
    gl2lds16(bStg2, d + 24576);
    aStg += 64; aStg2 += 64; bStg += 64; bStg2 += 64;
  }
  fence_vm<0>(); bar();

  const int rl = lane & 15, c4 = lane >> 4;
  const int sw0 = (c4 ^ (rl & 7)) * 8;
  const int sw1 = ((4 | c4) ^ (rl & 7)) * 8;
  const int aOff = (wr * 64 + rl) * 64;
  const int bOff = 16384 + (wc * 64 + rl) * 64;

  const ushort_t* rSlot = lds;
  ushort_t*       wSlot = lds + SLOT;

  for (int t = 0; t < NT; ++t) {
    if (t + 1 < NT) {
      gl2lds16(aStg,  wSlot + wo);
      gl2lds16(aStg2, wSlot + 8192 + wo);
      gl2lds16(bStg,  wSlot + 16384 + wo);
      gl2lds16(bStg2, wSlot + 24576 + wo);
      aStg += 64; aStg2 += 64; bStg += 64; bStg2 += 64;
    }

    const ushort_t* ra0 = rSlot + aOff + sw0;
    const ushort_t* ra1 = rSlot + aOff + sw1;
    const ushort_t* rb0 = rSlot + bOff + sw0;
    const ushort_t* rb1 = rSlot + bOff + sw1;

    {
      short8 af[4], bf[4];
      #pragma unroll
      for (int m = 0; m < 4; m++) af[m] = *(const short8*)(ra0 + m * 1024);
      #pragma unroll
      for (int n = 0; n < 4; n++) bf[n] = *(const short8*)(rb0 + n * 1024);
      __builtin_amdgcn_s_setprio(1);
      #pragma unroll
      for (int m = 0; m < 4; m++)
        #pragma unroll
        for (int n = 0; n < 4; n++)
          acc[m][n] = __builtin_amdgcn_mfma_f32_16x16x32_bf16(af[m], bf[n], acc[m][n], 0, 0, 0);
      __builtin_amdgcn_s_setprio(0);
    }
    {
      short8 af[4], bf[4];
      #pragma unroll
      for (int m = 0; m < 4; m++) af[m] = *(const short8*)(ra1 + m * 1024);
      #pragma unroll
      for (int n = 0; n < 4; n++) bf[n] = *(const short8*)(rb1 + n * 1024);
      __builtin_amdgcn_s_setprio(1);
      #pragma unroll
      for (int m = 0; m < 4; m++)
        #pragma unroll
        for (int n = 0; n < 4; n++)
          acc[m][n] = __builtin_amdgcn_mfma_f32_16x16x32_bf16(af[m], bf[n], acc[m][n], 0, 0, 0);
      __builtin_amdgcn_s_setprio(0);
    }

    if (t + 1 < NT) { fence_vm<0>(); bar(); }
    const ushort_t* tmp = rSlot; rSlot = wSlot; wSlot = (ushort_t*)tmp;
  }

  const int colb = n0 + wc * 64 + rl;
  const int rowb = m0 + wr * 64 + c4 * 4;
  #pragma unroll
  for (int n = 0; n < 4; n++) {
    int col = colb + n * 16;
    float bs = bias[col];
    #pragma unroll
    for (int m = 0; m < 4; m++) {
      int row = rowb + m * 16;
      #pragma unroll
      for (int j = 0; j < 4; j++) {
        float v = acc[m][n][j] + bs;
        float g = v / (1.f + __expf(-1.702f * v));
        outp[(size_t)(row + j) * N + col] = f2bf(g);
      }
    }
  }
}

// ========== gemm2: 256x128, BK=64, 3-slot (144 KB), 16 waves, wave tile 64x32 ==========
template <int K, int MODE>
__global__ __launch_bounds__(1024, 4) void gemm16v(const ushort_t* __restrict__ A,
                                                   const ushort_t* __restrict__ B,
                                                   const float* __restrict__ bias,
                                                   const float* __restrict__ resid,
                                                   void* __restrict__ outp,
                                                   int M, int N) {
  constexpr int TILEA = 16384;
  constexpr int SLOT  = TILEA + 8192;
  constexpr int NT = K / 64;
  __shared__ __align__(16) ushort_t lds[3 * SLOT];   // 144 KB

  const int tid = threadIdx.x;
  const int wave = tid >> 6, lane = tid & 63;
  const int wr = wave >> 2, wc = wave & 3;

  const int nwg = gridDim.x, cpx = nwg >> 3, bid = blockIdx.x;
  const int wg = (bid & 7) * cpx + (bid >> 3);
  const int nbn = N / 128;
  const int m0 = (wg / nbn) * 256, n0 = (wg % nbn) * 128;

  const int scol = 8 * ((tid & 7) ^ ((tid >> 3) & 7));
  const int wo = wave * 512;

  const ushort_t* aStgLo = A + (size_t)(m0 + (tid >> 3)) * K + scol;
  const ushort_t* aStgHi = aStgLo + (size_t)128 * K;
  const ushort_t* bStg   = B + (size_t)(n0 + (tid >> 3)) * K + scol;

  f32x4 acc[4][2] = {};

  {
    ushort_t* s0p = lds;
    gl2lds16(aStgLo, s0p + wo);
    gl2lds16(aStgHi, s0p + 8192 + wo);
    gl2lds16(bStg,   s0p + TILEA + wo);
    ushort_t* s1p = lds + SLOT;
    gl2lds16(aStgLo + 64, s1p + wo);
    gl2lds16(aStgHi + 64, s1p + 8192 + wo);
    gl2lds16(bStg   + 64, s1p + TILEA + wo);
    aStgLo += 128; aStgHi += 128; bStg += 128;
  }
  fence_vm<3>(); bar();

  const int rl = lane & 15, c4 = lane >> 4;
  const int sw0 = (c4 ^ (rl & 7)) * 8;
  const int sw1 = ((4 | c4) ^ (rl & 7)) * 8;
  const int aOff = (wr * 64 + rl) * 64;
  const int bOff = TILEA + (wc * 32 + rl) * 64;

  const ushort_t* rSlot = lds;
  ushort_t*       wSlot = lds + 2 * SLOT;

  for (int t = 0; t < NT; ++t) {
    const ushort_t* ra0 = rSlot + aOff + sw0;
    const ushort_t* ra1 = rSlot + aOff + sw1;
    const ushort_t* rb0 = rSlot + bOff + sw0;
    const ushort_t* rb1 = rSlot + bOff + sw1;

    short8 af[2][4], bf[2][2];
    #pragma unroll
    for (int m = 0; m < 4; m++) {
      af[0][m] = *(const short8*)(ra0 + m * 1024);
      af[1][m] = *(const short8*)(ra1 + m * 1024);
    }
    #pragma unroll
    for (int n = 0; n < 2; n++) {
      bf[0][n] = *(const short8*)(rb0 + n * 1024);
      bf[1][n] = *(const short8*)(rb1 + n * 1024);
    }

    if (t + 2 < NT) {
      gl2lds16(aStgLo, wSlot + wo);
      gl2lds16(aStgHi, wSlot + 8192 + wo);
      gl2lds16(bStg,   wSlot + TILEA + wo);
      aStgLo += 64; aStgHi += 64; bStg += 64;
    }

    __builtin_amdgcn_s_setprio(1);
    #pragma unroll
    for (int kk = 0; kk < 2; kk++)
      #pragma unroll
      for (int m = 0; m < 4; m++)
        #pragma unroll
        for (int n = 0; n < 2; n++)
          acc[m][n] = __builtin_amdgcn_mfma_f32_16x16x32_bf16(af[kk][m], bf[kk][n],
                                                              acc[m][n], 0, 0, 0);
    __builtin_amdgcn_s_setprio(0);

    if (t + 2 < NT) fence_vm<3>();
    else            fence_vm<0>();
    bar();

    const ushort_t* rn = rSlot + SLOT;
    rSlot = (rn == lds + 3 * SLOT) ? lds : rn;
    ushort_t* wn = wSlot + SLOT;
    wSlot = (wn == lds + 3 * SLOT) ? lds : wn;
  }

  const int colb = n0 + wc * 32 + rl;
  const int rowb = m0 + wr * 64 + c4 * 4;
  #pragma unroll
  for (int n = 0; n < 2; n++) {
    int col = colb + n * 16;
    float bs = bias[col];
    #pragma unroll
    for (int m = 0; m < 4; m++) {
      int row = rowb + m * 16;
      #pragma unroll
      for (int j = 0; j < 4; j++) {
        float v = acc[m][n][j] + bs;
        size_t o = (size_t)(row + j) * N + col;
        if (MODE == 1) {
          float g = v / (1.f + __expf(-1.702f * v));
          ((ushort_t*)outp)[o] = f2bf(g);
        } else {
          ((float*)outp)[o] = resid[o] + v;
        }
      }
    }
  }
}

// ---------------- launch ----------------
extern "C" void kernel_launch(void* const* d_in, const int* in_sizes, int n_in,
                              void* d_out, int out_size, void* d_ws, size_t ws_size,
                              hipStream_t stream) {
  (void)in_sizes; (void)n_in; (void)out_size; (void)ws_size;
  const float* x      = (const float*)d_in[0];
  const float* A_ssm  = (const float*)d_in[1];
  const float* B_ssm  = (const float*)d_in[2];
  const float* C_ssm  = (const float*)d_in[3];
  const float* D_ssm  = (const float*)d_in[4];
  const float* scale1 = (const float*)d_in[5];
  const float* scale2 = (const float*)d_in[6];
  const float* w1     = (const float*)d_in[7];
  const float* b1     = (const float*)d_in[8];
  const float* w2     = (const float*)d_in[9];
  const float* b2     = (const float*)d_in[10];
  float* out = (float*)d_out;

  char* ws = (char*)d_ws;
  float*    rrms  = (float*)(ws + 0);                         // 32 KB
  float*    dA_t  = (float*)(ws + 32768);                     // 64 KB
  float*    dBz_t = (float*)(ws + 98304);                     // 64 KB
  float*    dAc_t = (float*)(ws + 163840);                    // 64 KB
  float*    Ct    = (float*)(ws + 229376);                    // 64 KB
  float*    s_fin = (float*)(ws + 294912);                    // 8 MB
  float*    s_in  = (float*)(ws + 8683520);                   // 8 MB
  ushort_t* hb    = (ushort_t*)(ws + 17072128);               // 16 MB
  ushort_t* w1t   = (ushort_t*)(ws + 33849344);               // 8 MB
  ushort_t* w2t   = (ushort_t*)(ws + 42237952);               // 8 MB
  ushort_t* gb    = (ushort_t*)(ws + 50626560);               // 64 MB

  const int ROWS = BATCH * SEQLEN;  // 8192

  coef_kernel<<<DMODEL / 256, 256, 0, stream>>>(A_ssm, B_ssm, C_ssm, dA_t, dBz_t, dAc_t, Ct);
  transpose_to_bf16<<<dim3(DFF / 32, DMODEL / 32), dim3(32, 8), 0, stream>>>(w1, w1t, DMODEL, DFF);
  transpose_to_bf16<<<dim3(DMODEL / 32, DFF / 32), dim3(32, 8), 0, stream>>>(w2, w2t, DFF, DMODEL);
  rms1_kernel<<<ROWS / 4, 256, 0, stream>>>(x, rrms);
  scan_pass1<<<dim3(DMODEL / 256, BATCH, NCH), 256, 0, stream>>>(x, rrms, scale1, dA_t, dBz_t, s_fin);
  scan_pass2<<<(BATCH * DMODEL * NSTATE) / 256, 256, 0, stream>>>(s_fin, dAc_t, s_in);
  scan_pass3<<<dim3(DMODEL / 256, BATCH, NCH), 256, 0, stream>>>(x, rrms, scale1, dA_t, dBz_t, Ct,
                                                                 D_ssm, s_in, out);
  rms2_kernel<<<ROWS / 4, 256, 0, stream>>>(out, scale2, hb);

  // gemm1: [8192x1024]@[1024x4096] -> gelu -> gb (bf16). 512 blocks, 256x256, BK=64.
  gemm_w64<DMODEL><<<(ROWS / 256) * (DFF / 256), 1024, 0, stream>>>(
      hb, w1t, b1, gb, ROWS, DFF);
  // gemm2: [8192x4096]@[4096x1024] + resid -> out (f32). 256 blocks, 256x128, BK=64.
  gemm16v<DFF, 2><<<(ROWS / 256) * (DMODEL / 128), 1024, 0, stream>>>(
      gb, w2t, b2, out, out, ROWS, DMODEL);
}